// Round 8
// baseline (1062.336 us; speedup 1.0000x reference)
//
#include <hip/hip_runtime.h>
#include <hip/hip_bf16.h>
#include <cstdint>
#include <math.h>

// Problem constants
#define NB 512
#define NS 128
#define ND 512
#define NH 8
#define NDK 64
#define NFF 2048

typedef __attribute__((ext_vector_type(4))) float f32x4;
typedef __attribute__((ext_vector_type(8))) short s16x8;

#define AS1 __attribute__((address_space(1)))
#define AS3 __attribute__((address_space(3)))

__device__ __forceinline__ ushort f2b(float f) {
  __hip_bfloat16 h = __float2bfloat16(f);
  return *reinterpret_cast<ushort*>(&h);
}
__device__ __forceinline__ float b2f(ushort u) {
  __hip_bfloat16 h;
  *reinterpret_cast<ushort*>(&h) = u;
  return __bfloat162float(h);
}
// global -> LDS direct copy, 16B per lane. LDS dest is wave-uniform base;
// HW writes base + lane*16. Global src is per-lane (enables swizzled staging).
__device__ __forceinline__ void gll16(const void* g, void* l) {
  __builtin_amdgcn_global_load_lds(
      (const AS1 unsigned int*)g,
      reinterpret_cast<AS3 unsigned int*>(reinterpret_cast<uintptr_t>(l)),
      16, 0, 0);
}

// ---------------------------------------------------------------- pack kernels
__global__ void conv_bf16(const float* __restrict__ in, ushort* __restrict__ out, int n4) {
  int i = blockIdx.x * blockDim.x + threadIdx.x;
  if (i >= n4) return;
  float4 v = *(const float4*)(in + (size_t)i * 4);
  ushort4 o;
  o.x = f2b(v.x); o.y = f2b(v.y); o.z = f2b(v.z); o.w = f2b(v.w);
  *(ushort4*)(out + (size_t)i * 4) = o;
}

// transpose-convert: in [R][C] fp32 -> out [C][R] bf16
__global__ void pack_t(const float* __restrict__ in, ushort* __restrict__ out, int R, int C) {
  int i = blockIdx.x * blockDim.x + threadIdx.x;
  if (i >= R * C) return;
  int r = i / C, c = i - r * C;
  out[(size_t)c * R + r] = f2b(in[i]);
}

// wqkvT[h][n][d]: n<64 -> WQ[h][d][n]*0.125 ; n<128 -> WK ; else WV
__global__ void pack_qkv(const float* __restrict__ WQ, const float* __restrict__ WK,
                         const float* __restrict__ WV, ushort* __restrict__ out) {
  int i = blockIdx.x * blockDim.x + threadIdx.x;
  if (i >= NH * 192 * ND) return;
  int h = i / (192 * ND);
  int rem = i - h * (192 * ND);
  int n = rem / ND, d = rem - n * ND;
  size_t base = (size_t)h * ND * NDK + (size_t)d * NDK;
  float v;
  if (n < 64)       v = WQ[base + n] * 0.125f;
  else if (n < 128) v = WK[base + (n - 64)];
  else              v = WV[base + (n - 128)];
  out[i] = f2b(v);
}

__global__ void pe_build(float* __restrict__ pe) {
  int i = blockIdx.x * blockDim.x + threadIdx.x;
  if (i >= NS * ND) return;
  int s = i >> 9, d = i & 511;
  float e = expf((float)(d & ~1) * (-9.210340371976184f / 512.f)); // ln(10000)
  float ang = (float)s * e;
  pe[i] = (d & 1) ? cosf(ang) : sinf(ang);
}

// ---------------------------------------------------------------- generic GEMM
// C[M,N] = A[M,K](bf16) @ Bt[N,K]^T(bf16), 128x128 tile, BK=32, dbuf m97-style.
// EPI 0: +bias +PE -> bf16 Obf (embed->h)
// EPI 1: +res(bf16 h) -> fp32 Of (r) + LN stats atomics
// EPI 2: +bias, relu -> bf16 Obf (ffn1)
// EPI 3: +bias, fused 16x16 maxpool -> pool[b][256]
// EPI 4: QKV scatter: Obf=qb, Of=kb(cast), pool=vtb(cast); v written transposed
template <int EPI>
__global__ __launch_bounds__(256, 2) void gemm_bf16(
    const ushort* __restrict__ A, const ushort* __restrict__ Bt,
    int M, int N, int K,
    ushort* __restrict__ Obf, float* __restrict__ Of,
    const float* __restrict__ bias, const float* __restrict__ pe,
    const ushort* __restrict__ res, float* __restrict__ stats,
    float* __restrict__ pool) {
  __shared__ __align__(16) ushort lA[2][4096];  // [128][32]
  __shared__ __align__(16) ushort lB[2][4096];  // [128][32]
  const int tid = threadIdx.x, lane = tid & 63, wid = tid >> 6;
  const int wr = wid >> 1, wc = wid & 1;
  const int lo = lane & 15, hi = lane >> 4;
  const int ntil = N >> 7;
  const int bm = blockIdx.x / ntil, bn = blockIdx.x - bm * ntil;
  const int m0 = bm << 7, n0 = bn << 7;
  const int rr = lane >> 2, cc = (lane & 3) << 3;

  f32x4 acc[4][4];
#pragma unroll
  for (int m = 0; m < 4; ++m)
#pragma unroll
    for (int n = 0; n < 4; ++n) acc[m][n] = (f32x4){0.f, 0.f, 0.f, 0.f};

  const int nk = K >> 5;
  for (int s = wid; s < 8; s += 4) {
    gll16(&A[(size_t)(m0 + s * 16 + rr) * K + cc], &lA[0][s * 512]);
    gll16(&Bt[(size_t)(n0 + s * 16 + rr) * K + cc], &lB[0][s * 512]);
  }
  __syncthreads();
  for (int t = 0; t < nk; ++t) {
    const int cur = t & 1;
    if (t + 1 < nk) {
      const int k0 = (t + 1) << 5;
      for (int s = wid; s < 8; s += 4) {
        gll16(&A[(size_t)(m0 + s * 16 + rr) * K + k0 + cc], &lA[cur ^ 1][s * 512]);
        gll16(&Bt[(size_t)(n0 + s * 16 + rr) * K + k0 + cc], &lB[cur ^ 1][s * 512]);
      }
    }
    s16x8 af[4], bfr[4];
#pragma unroll
    for (int m = 0; m < 4; ++m)
      af[m] = *(const s16x8*)&lA[cur][(wr * 64 + m * 16 + lo) * 32 + hi * 8];
#pragma unroll
    for (int n = 0; n < 4; ++n)
      bfr[n] = *(const s16x8*)&lB[cur][(wc * 64 + n * 16 + lo) * 32 + hi * 8];
#pragma unroll
    for (int m = 0; m < 4; ++m)
#pragma unroll
      for (int n = 0; n < 4; ++n)
        acc[m][n] = __builtin_amdgcn_mfma_f32_16x16x32_bf16(af[m], bfr[n], acc[m][n], 0, 0, 0);
    __syncthreads();
  }

  if constexpr (EPI == 0) {
#pragma unroll
    for (int m = 0; m < 4; ++m)
#pragma unroll
      for (int n = 0; n < 4; ++n) {
        const int col = n0 + wc * 64 + n * 16 + lo;
        const float bv = bias[col];
#pragma unroll
        for (int j = 0; j < 4; ++j) {
          const int row = m0 + wr * 64 + m * 16 + hi * 4 + j;
          const float v = acc[m][n][j] + bv + pe[((row & 127) << 9) + col];
          Obf[(size_t)row * N + col] = f2b(v);
        }
      }
  } else if constexpr (EPI == 1) {
    float s1 = 0.f, s2 = 0.f;
#pragma unroll
    for (int m = 0; m < 4; ++m)
#pragma unroll
      for (int n = 0; n < 4; ++n) {
        const int col = n0 + wc * 64 + n * 16 + lo;
#pragma unroll
        for (int j = 0; j < 4; ++j) {
          const int row = m0 + wr * 64 + m * 16 + hi * 4 + j;
          const float v = acc[m][n][j] + b2f(res[(size_t)row * 512 + col]);
          Of[(size_t)row * 512 + col] = v;
          s1 += v; s2 += v * v;
        }
      }
    s1 += __shfl_xor(s1, 1);  s2 += __shfl_xor(s2, 1);
    s1 += __shfl_xor(s1, 2);  s2 += __shfl_xor(s2, 2);
    s1 += __shfl_xor(s1, 4);  s2 += __shfl_xor(s2, 4);
    s1 += __shfl_xor(s1, 8);  s2 += __shfl_xor(s2, 8);
    s1 += __shfl_xor(s1, 16); s2 += __shfl_xor(s2, 16);
    s1 += __shfl_xor(s1, 32); s2 += __shfl_xor(s2, 32);
    if (lane == 0) {
      atomicAdd(&stats[bm * 2], s1);
      atomicAdd(&stats[bm * 2 + 1], s2);
    }
  } else if constexpr (EPI == 2) {
#pragma unroll
    for (int m = 0; m < 4; ++m)
#pragma unroll
      for (int n = 0; n < 4; ++n) {
        const int col = n0 + wc * 64 + n * 16 + lo;
        const float bv = bias[col];
#pragma unroll
        for (int j = 0; j < 4; ++j) {
          const int row = m0 + wr * 64 + m * 16 + hi * 4 + j;
          Obf[(size_t)row * N + col] = f2b(fmaxf(acc[m][n][j] + bv, 0.f));
        }
      }
  } else if constexpr (EPI == 3) {  // fused maxpool 16x16 -> pool[b*256 + sg*32 + dg]
#pragma unroll
    for (int m = 0; m < 4; ++m)
#pragma unroll
      for (int n = 0; n < 4; ++n) {
        const int col = n0 + wc * 64 + n * 16 + lo;
        float fv = fmaxf(fmaxf(acc[m][n][0], acc[m][n][1]),
                         fmaxf(acc[m][n][2], acc[m][n][3])) + bias[col];
        fv = fmaxf(fv, __shfl_xor(fv, 1));
        fv = fmaxf(fv, __shfl_xor(fv, 2));
        fv = fmaxf(fv, __shfl_xor(fv, 4));
        fv = fmaxf(fv, __shfl_xor(fv, 8));
        fv = fmaxf(fv, __shfl_xor(fv, 16));
        fv = fmaxf(fv, __shfl_xor(fv, 32));
        if (lane == 0)
          pool[bm * 256 + (wr * 4 + m) * 32 + (bn * 8 + wc * 4 + n)] = fv;
      }
  } else {  // EPI 4: QKV scatter. col -> (h, kind, idx); q,k row-major, v transposed
    ushort* kbp = (ushort*)Of;
    ushort* vtp = (ushort*)pool;
#pragma unroll
    for (int m = 0; m < 4; ++m)
#pragma unroll
      for (int n = 0; n < 4; ++n) {
        const int cn0 = n0 + wc * 64 + n * 16;
        const int h = cn0 / 192;
        const int rem = cn0 - h * 192;
        const int kind = rem >> 6;
        const int idx = (rem & 63) + lo;
#pragma unroll
        for (int j = 0; j < 4; ++j) {
          const int row = m0 + wr * 64 + m * 16 + hi * 4 + j;
          const size_t hb = (size_t)((row >> 7) * 8 + h) * 8192;
          const ushort v = f2b(acc[m][n][j]);
          if (kind == 0)      Obf[hb + (row & 127) * 64 + idx] = v;
          else if (kind == 1) kbp[hb + (row & 127) * 64 + idx] = v;
          else                vtp[hb + (size_t)idx * 128 + (row & 127)] = v;
        }
      }
  }
}

// ---------------------------------------------------------------- attention core
// one block per (b,head). Inputs qb,kb [bh][128][64] (q pre-scaled), vtb [bh][64][128].
// All LDS MFMA operands chunk-XOR swizzled -> <=2-way bank conflicts.
__global__ __launch_bounds__(256, 3) void attn_core(
    const ushort* __restrict__ qb, const ushort* __restrict__ kb,
    const ushort* __restrict__ vtb, ushort* __restrict__ o) {
  // smem ushorts: q [0,8192) rows of 64, k [8192,16384), vT [16384,24576) rows of 128
  // P [128][128] overlays [0,16384) after scores.
  __shared__ __align__(16) ushort smem[24576];
  const int tid = threadIdx.x, lane = tid & 63, wid = tid >> 6;
  const int lo = lane & 15, hi = lane >> 4;
  const int bh = blockIdx.x;
  const size_t base = (size_t)bh * 8192;

  // stage q,k,vT: linear LDS dest, chunk-XOR pre-swizzled global src
#pragma unroll
  for (int i = 0; i < 4; ++i) {
    const int Lb = (wid * 4 + i) * 64;
    const int L = Lb + lane;
    {
      const int r = L >> 3, c = L & 7;  // q: 8 chunks/row
      gll16(&qb[base + r * 64 + ((c ^ (r & 7)) << 3)], &smem[Lb * 8]);
      gll16(&kb[base + r * 64 + ((c ^ (r & 7)) << 3)], &smem[8192 + Lb * 8]);
    }
    {
      const int r = L >> 4, c = L & 15;  // vT: 16 chunks/row
      gll16(&vtb[base + r * 128 + ((c ^ (r & 15)) << 3)], &smem[16384 + Lb * 8]);
    }
  }
  __syncthreads();

  // ---- scores: rows [wid*32,+32) x cols 128 (q pre-scaled by 1/8)
  f32x4 sc[2][8];
#pragma unroll
  for (int m = 0; m < 2; ++m)
#pragma unroll
    for (int n = 0; n < 8; ++n) sc[m][n] = (f32x4){0.f, 0.f, 0.f, 0.f};
#pragma unroll
  for (int kt = 0; kt < 2; ++kt) {
    s16x8 aq[2], bk[8];
#pragma unroll
    for (int m = 0; m < 2; ++m) {
      const int row = wid * 32 + m * 16 + lo;
      aq[m] = *(const s16x8*)&smem[row * 64 + (((kt * 4 + hi) ^ (row & 7)) << 3)];
    }
#pragma unroll
    for (int n = 0; n < 8; ++n) {
      const int kr = n * 16 + lo;
      bk[n] = *(const s16x8*)&smem[8192 + kr * 64 + (((kt * 4 + hi) ^ (kr & 7)) << 3)];
    }
#pragma unroll
    for (int m = 0; m < 2; ++m)
#pragma unroll
      for (int n = 0; n < 8; ++n)
        sc[m][n] = __builtin_amdgcn_mfma_f32_16x16x32_bf16(aq[m], bk[n], sc[m][n], 0, 0, 0);
  }
  __syncthreads();  // q,k reads done; safe to overlay P

  // ---- softmax per row (row = wid*32 + m*16 + hi*4 + j; full row within wave)
  float inv[2][4];
#pragma unroll
  for (int m = 0; m < 2; ++m)
#pragma unroll
    for (int j = 0; j < 4; ++j) {
      float mx = sc[m][0][j];
#pragma unroll
      for (int n = 1; n < 8; ++n) mx = fmaxf(mx, sc[m][n][j]);
      mx = fmaxf(mx, __shfl_xor(mx, 1));
      mx = fmaxf(mx, __shfl_xor(mx, 2));
      mx = fmaxf(mx, __shfl_xor(mx, 4));
      mx = fmaxf(mx, __shfl_xor(mx, 8));
      float s = 0.f;
#pragma unroll
      for (int n = 0; n < 8; ++n) {
        const float p = __expf(sc[m][n][j] - mx);
        sc[m][n][j] = p;
        s += p;
      }
      s += __shfl_xor(s, 1);
      s += __shfl_xor(s, 2);
      s += __shfl_xor(s, 4);
      s += __shfl_xor(s, 8);
      inv[m][j] = 1.f / s;
    }
  // write P (chunk-XOR swizzled), overlays q+k
#pragma unroll
  for (int m = 0; m < 2; ++m)
#pragma unroll
    for (int n = 0; n < 8; ++n)
#pragma unroll
      for (int j = 0; j < 4; ++j) {
        const int row = wid * 32 + m * 16 + hi * 4 + j;
        const int col = n * 16 + lo;
        smem[row * 128 + ((((col >> 3) ^ (row & 15)) << 3) | (col & 7))] =
            f2b(sc[m][n][j]);
      }
  __syncthreads();

  // ---- PV: O[rows 32/wave][64], K=128
  f32x4 oa[2][4];
#pragma unroll
  for (int m = 0; m < 2; ++m)
#pragma unroll
    for (int n = 0; n < 4; ++n) oa[m][n] = (f32x4){0.f, 0.f, 0.f, 0.f};
#pragma unroll
  for (int kt = 0; kt < 4; ++kt) {
    s16x8 ap[2], bv[4];
#pragma unroll
    for (int m = 0; m < 2; ++m) {
      const int row = wid * 32 + m * 16 + lo;
      ap[m] = *(const s16x8*)&smem[row * 128 + (((kt * 4 + hi) ^ (row & 15)) << 3)];
    }
#pragma unroll
    for (int n = 0; n < 4; ++n) {
      const int vr = n * 16 + lo;
      bv[n] = *(const s16x8*)&smem[16384 + vr * 128 + (((kt * 4 + hi) ^ (vr & 15)) << 3)];
    }
#pragma unroll
    for (int m = 0; m < 2; ++m)
#pragma unroll
      for (int n = 0; n < 4; ++n)
        oa[m][n] = __builtin_amdgcn_mfma_f32_16x16x32_bf16(ap[m], bv[n], oa[m][n], 0, 0, 0);
  }
  const int b = bh >> 3, hd = bh & 7;
#pragma unroll
  for (int m = 0; m < 2; ++m)
#pragma unroll
    for (int n = 0; n < 4; ++n)
#pragma unroll
      for (int j = 0; j < 4; ++j) {
        const int row = wid * 32 + m * 16 + hi * 4 + j;
        const int col = n * 16 + lo;
        o[(size_t)b * 65536 + row * 512 + hd * 64 + col] = f2b(oa[m][n][j] * inv[m][j]);
      }
}

// ---------------------------------------------------------------- LN apply (fp32 in)
__global__ void ln_apply(const float* __restrict__ r, const float* __restrict__ stats,
                         const float* __restrict__ nw, const float* __restrict__ nb,
                         ushort* __restrict__ rn) {
  int i = blockIdx.x * blockDim.x + threadIdx.x;  // x4 elements
  int base = i << 2;
  if (base >= NB * NS * ND) return;
  int b = base >> 16;     // / (S*D=65536)
  int sd = base & 65535;
  float mu = stats[2 * b] * (1.f / 65536.f);
  float var = stats[2 * b + 1] * (1.f / 65536.f) - mu * mu;
  float rs = rsqrtf(var + 1e-5f);
  float4 rv = *(const float4*)(r + base);
  float4 w = *(const float4*)(nw + sd);
  float4 bb = *(const float4*)(nb + sd);
  ushort4 ov;
  ov.x = f2b((rv.x - mu) * rs * w.x + bb.x);
  ov.y = f2b((rv.y - mu) * rs * w.y + bb.y);
  ov.z = f2b((rv.z - mu) * rs * w.z + bb.z);
  ov.w = f2b((rv.w - mu) * rs * w.w + bb.w);
  *(ushort4*)(rn + base) = ov;
}

// ---------------------------------------------------------------- final fc
__global__ void fc_logsoftmax(const float* __restrict__ p, const float* __restrict__ w,
                              const float* __restrict__ bias, float* __restrict__ out) {
  int b = blockIdx.x * blockDim.x + threadIdx.x;
  if (b >= NB) return;
  float l0 = bias[0], l1 = bias[1];
  const float* pr = p + b * 256;
  for (int k = 0; k < 256; ++k) {
    float pv = pr[k];
    l0 += pv * w[2 * k];
    l1 += pv * w[2 * k + 1];
  }
  float mx = fmaxf(l0, l1);
  float lse = mx + logf(expf(l0 - mx) + expf(l1 - mx));
  out[2 * b] = l0 - lse;
  out[2 * b + 1] = l1 - lse;
}

// ---------------------------------------------------------------- launch
extern "C" void kernel_launch(void* const* d_in, const int* in_sizes, int n_in,
                              void* d_out, int out_size, void* d_ws, size_t ws_size,
                              hipStream_t stream) {
  const float* x      = (const float*)d_in[0];
  const float* emb_w  = (const float*)d_in[1];
  const float* emb_b  = (const float*)d_in[2];
  const float* WQ     = (const float*)d_in[3];
  const float* WK     = (const float*)d_in[4];
  const float* WV     = (const float*)d_in[5];
  const float* WO     = (const float*)d_in[6];
  const float* norm_w = (const float*)d_in[7];
  const float* norm_b = (const float*)d_in[8];
  const float* l1_w   = (const float*)d_in[9];
  const float* l1_b   = (const float*)d_in[10];
  const float* l2_w   = (const float*)d_in[11];
  const float* l2_b   = (const float*)d_in[12];
  const float* fc_w   = (const float*)d_in[13];
  const float* fc_b   = (const float*)d_in[14];
  float* out = (float*)d_out;
  char* ws = (char*)d_ws;

  constexpr size_t MB = 1ull << 20;
  // Lifetime-overlaid layout (peak 392 MB, same as the proven R4 footprint):
  ushort* xb    = (ushort*)(ws + 0);          // 64 MB (dead after embed)
  ushort* qb    = (ushort*)(ws + 0);          // 64 MB [bh][128][64] (over xb)
  ushort* hbuf  = (ushort*)(ws + 64 * MB);    // 64 MB (live until WO residual)
  ushort* kbuf  = (ushort*)(ws + 128 * MB);   // 64 MB [bh][128][64]
  ushort* obuf  = (ushort*)(ws + 192 * MB);   // 64 MB (attn out; read by WO gemm)
  ushort* vtb   = (ushort*)(ws + 256 * MB);   // 64 MB [bh][64][128] (dead after attn)
  float*  rbuf  = (float*)(ws + 256 * MB);    // 128 MB fp32 r (over vtb; no overlap w/ obuf)
  ushort* rnb   = (ushort*)(ws + 64 * MB);    // 64 MB (over hbuf, dead after WO gemm)
  ushort* f1    = (ushort*)(ws + 128 * MB);   // 256 MB [128,384): kbuf/obuf/rbuf dead by FFN1
  char* wb = ws + 384 * MB;
  ushort* embT  = (ushort*)(wb);                  // 512 KB
  ushort* woT   = (ushort*)(wb + 524288);         // 512 KB
  ushort* l1T   = (ushort*)(wb + 1048576);        // 2 MB
  ushort* l2T   = (ushort*)(wb + 3145728);        // 2 MB
  ushort* wqkvT = (ushort*)(wb + 5242880);        // 1.5 MB
  float*  peb   = (float*)(wb + 6815744);         // 256 KB
  float*  stats = (float*)(wb + 7077888);         // 4 KB
  float*  poolb = (float*)(wb + 7081984);         // 512 KB

  hipMemsetAsync(stats, 0, NB * 2 * sizeof(float), stream);

  conv_bf16<<<32768, 256, 0, stream>>>(x, xb, NB * NS * ND / 4);
  pe_build<<<256, 256, 0, stream>>>(peb);
  pack_t<<<1024, 256, 0, stream>>>(emb_w, embT, 512, 512);
  pack_t<<<1024, 256, 0, stream>>>(WO, woT, 512, 512);
  pack_t<<<4096, 256, 0, stream>>>(l1_w, l1T, 512, 2048);
  pack_t<<<4096, 256, 0, stream>>>(l2_w, l2T, 2048, 512);
  pack_qkv<<<3072, 256, 0, stream>>>(WQ, WK, WV, wqkvT);

  // h = x@emb_w + emb_b + PE
  gemm_bf16<0><<<2048, 256, 0, stream>>>(xb, embT, NB * NS, ND, ND,
                                         hbuf, nullptr, emb_b, peb, nullptr, nullptr, nullptr);
  // q,k,vT for all heads in one GEMM: [65536,512] @ [512,1536]
  gemm_bf16<4><<<6144, 256, 0, stream>>>(hbuf, wqkvT, NB * NS, NH * 192, ND,
                                         qb, (float*)kbuf, nullptr, nullptr, nullptr, nullptr,
                                         (float*)vtb);
  // attention core -> o
  attn_core<<<NB * NH, 256, 0, stream>>>(qb, kbuf, vtb, obuf);
  // r = o@WO + h (fp32) + LN stats
  gemm_bf16<1><<<2048, 256, 0, stream>>>(obuf, woT, NB * NS, ND, ND,
                                         nullptr, rbuf, nullptr, nullptr, hbuf, stats, nullptr);
  // rn = LN(r)
  ln_apply<<<32768, 256, 0, stream>>>(rbuf, stats, norm_w, norm_b, rnb);
  // f1 = relu(rn@l1 + b1)
  gemm_bf16<2><<<8192, 256, 0, stream>>>(rnb, l1T, NB * NS, NFF, ND,
                                         f1, nullptr, l1_b, nullptr, nullptr, nullptr, nullptr);
  // pool = maxpool16x16(f1@l2 + b2)
  gemm_bf16<3><<<2048, 256, 0, stream>>>(f1, l2T, NB * NS, ND, NFF,
                                         nullptr, nullptr, l2_b, nullptr, nullptr, nullptr, poolb);
  // logits + log_softmax
  fc_logsoftmax<<<2, 256, 0, stream>>>(poolb, fc_w, fc_b, out);
}

// Round 9
// 1005.801 us; speedup vs baseline: 1.0562x; 1.0562x over previous
//
#include <hip/hip_runtime.h>
#include <hip/hip_bf16.h>
#include <cstdint>
#include <math.h>

// Problem constants
#define NB 512
#define NS 128
#define ND 512
#define NH 8
#define NDK 64
#define NFF 2048

typedef __attribute__((ext_vector_type(4))) float f32x4;
typedef __attribute__((ext_vector_type(8))) short s16x8;

#define AS1 __attribute__((address_space(1)))
#define AS3 __attribute__((address_space(3)))

__device__ __forceinline__ ushort f2b(float f) {
  __hip_bfloat16 h = __float2bfloat16(f);
  return *reinterpret_cast<ushort*>(&h);
}
__device__ __forceinline__ float b2f(ushort u) {
  __hip_bfloat16 h;
  *reinterpret_cast<ushort*>(&h) = u;
  return __bfloat162float(h);
}
// global -> LDS direct copy, 16B per lane. LDS dest is wave-uniform base;
// HW writes base + lane*16. Global src is per-lane (enables swizzled staging).
__device__ __forceinline__ void gll16(const void* g, void* l) {
  __builtin_amdgcn_global_load_lds(
      (const AS1 unsigned int*)g,
      reinterpret_cast<AS3 unsigned int*>(reinterpret_cast<uintptr_t>(l)),
      16, 0, 0);
}

// ---------------------------------------------------------------- pack kernels
__global__ void conv_bf16(const float* __restrict__ in, ushort* __restrict__ out, int n4) {
  int i = blockIdx.x * blockDim.x + threadIdx.x;
  if (i >= n4) return;
  float4 v = *(const float4*)(in + (size_t)i * 4);
  ushort4 o;
  o.x = f2b(v.x); o.y = f2b(v.y); o.z = f2b(v.z); o.w = f2b(v.w);
  *(ushort4*)(out + (size_t)i * 4) = o;
}

// transpose-convert: in [R][C] fp32 -> out [C][R] bf16
__global__ void pack_t(const float* __restrict__ in, ushort* __restrict__ out, int R, int C) {
  int i = blockIdx.x * blockDim.x + threadIdx.x;
  if (i >= R * C) return;
  int r = i / C, c = i - r * C;
  out[(size_t)c * R + r] = f2b(in[i]);
}

// wqkvT[h][n][d]: n<64 -> WQ[h][d][n]*0.125 ; n<128 -> WK ; else WV
__global__ void pack_qkv(const float* __restrict__ WQ, const float* __restrict__ WK,
                         const float* __restrict__ WV, ushort* __restrict__ out) {
  int i = blockIdx.x * blockDim.x + threadIdx.x;
  if (i >= NH * 192 * ND) return;
  int h = i / (192 * ND);
  int rem = i - h * (192 * ND);
  int n = rem / ND, d = rem - n * ND;
  size_t base = (size_t)h * ND * NDK + (size_t)d * NDK;
  float v;
  if (n < 64)       v = WQ[base + n] * 0.125f;
  else if (n < 128) v = WK[base + (n - 64)];
  else              v = WV[base + (n - 128)];
  out[i] = f2b(v);
}

__global__ void pe_build(float* __restrict__ pe) {
  int i = blockIdx.x * blockDim.x + threadIdx.x;
  if (i >= NS * ND) return;
  int s = i >> 9, d = i & 511;
  float e = expf((float)(d & ~1) * (-9.210340371976184f / 512.f)); // ln(10000)
  float ang = (float)s * e;
  pe[i] = (d & 1) ? cosf(ang) : sinf(ang);
}

// ---------------------------------------------------------------- generic GEMM
// C[M,N] = A[M,K](bf16) @ Bt[N,K]^T(bf16), 128x128 tile, BK=32, dbuf m97-style.
// T1 chunked XCD swizzle: contiguous logical blocks (sharing A-panels) land on
// one XCD so the A-panel is fetched once into its L2 (grids all %8==0).
// EPI 0: +bias +PE -> bf16 Obf (embed->h)
// EPI 1: +res(bf16 h) -> fp32 Of (r) + LN stats atomics
// EPI 2: +bias, relu -> bf16 Obf (ffn1)
// EPI 3: +bias, fused 16x16 maxpool -> pool[b][256]
// EPI 4: QKV scatter: Obf=qb, Of=kb(cast), pool=vtb(cast); v written transposed
template <int EPI>
__global__ __launch_bounds__(256, 2) void gemm_bf16(
    const ushort* __restrict__ A, const ushort* __restrict__ Bt,
    int M, int N, int K,
    ushort* __restrict__ Obf, float* __restrict__ Of,
    const float* __restrict__ bias, const float* __restrict__ pe,
    const ushort* __restrict__ res, float* __restrict__ stats,
    float* __restrict__ pool) {
  __shared__ __align__(16) ushort lA[2][4096];  // [128][32]
  __shared__ __align__(16) ushort lB[2][4096];  // [128][32]
  const int tid = threadIdx.x, lane = tid & 63, wid = tid >> 6;
  const int wr = wid >> 1, wc = wid & 1;
  const int lo = lane & 15, hi = lane >> 4;
  const int ntil = N >> 7;
  // T1: physical block bid runs on XCD (bid&7); remap so each XCD owns a
  // contiguous logical chunk (bijective: gridDim.x % 8 == 0 for all calls).
  const int cpx = gridDim.x >> 3;
  const int wg = (blockIdx.x & 7) * cpx + (blockIdx.x >> 3);
  const int bm = wg / ntil, bn = wg - bm * ntil;
  const int m0 = bm << 7, n0 = bn << 7;
  const int rr = lane >> 2, cc = (lane & 3) << 3;

  f32x4 acc[4][4];
#pragma unroll
  for (int m = 0; m < 4; ++m)
#pragma unroll
    for (int n = 0; n < 4; ++n) acc[m][n] = (f32x4){0.f, 0.f, 0.f, 0.f};

  const int nk = K >> 5;
  for (int s = wid; s < 8; s += 4) {
    gll16(&A[(size_t)(m0 + s * 16 + rr) * K + cc], &lA[0][s * 512]);
    gll16(&Bt[(size_t)(n0 + s * 16 + rr) * K + cc], &lB[0][s * 512]);
  }
  __syncthreads();
  for (int t = 0; t < nk; ++t) {
    const int cur = t & 1;
    if (t + 1 < nk) {
      const int k0 = (t + 1) << 5;
      for (int s = wid; s < 8; s += 4) {
        gll16(&A[(size_t)(m0 + s * 16 + rr) * K + k0 + cc], &lA[cur ^ 1][s * 512]);
        gll16(&Bt[(size_t)(n0 + s * 16 + rr) * K + k0 + cc], &lB[cur ^ 1][s * 512]);
      }
    }
    s16x8 af[4], bfr[4];
#pragma unroll
    for (int m = 0; m < 4; ++m)
      af[m] = *(const s16x8*)&lA[cur][(wr * 64 + m * 16 + lo) * 32 + hi * 8];
#pragma unroll
    for (int n = 0; n < 4; ++n)
      bfr[n] = *(const s16x8*)&lB[cur][(wc * 64 + n * 16 + lo) * 32 + hi * 8];
#pragma unroll
    for (int m = 0; m < 4; ++m)
#pragma unroll
      for (int n = 0; n < 4; ++n)
        acc[m][n] = __builtin_amdgcn_mfma_f32_16x16x32_bf16(af[m], bfr[n], acc[m][n], 0, 0, 0);
    __syncthreads();
  }

  if constexpr (EPI == 0) {
#pragma unroll
    for (int m = 0; m < 4; ++m)
#pragma unroll
      for (int n = 0; n < 4; ++n) {
        const int col = n0 + wc * 64 + n * 16 + lo;
        const float bv = bias[col];
#pragma unroll
        for (int j = 0; j < 4; ++j) {
          const int row = m0 + wr * 64 + m * 16 + hi * 4 + j;
          const float v = acc[m][n][j] + bv + pe[((row & 127) << 9) + col];
          Obf[(size_t)row * N + col] = f2b(v);
        }
      }
  } else if constexpr (EPI == 1) {
    float s1 = 0.f, s2 = 0.f;
#pragma unroll
    for (int m = 0; m < 4; ++m)
#pragma unroll
      for (int n = 0; n < 4; ++n) {
        const int col = n0 + wc * 64 + n * 16 + lo;
#pragma unroll
        for (int j = 0; j < 4; ++j) {
          const int row = m0 + wr * 64 + m * 16 + hi * 4 + j;
          const float v = acc[m][n][j] + b2f(res[(size_t)row * 512 + col]);
          Of[(size_t)row * 512 + col] = v;
          s1 += v; s2 += v * v;
        }
      }
    s1 += __shfl_xor(s1, 1);  s2 += __shfl_xor(s2, 1);
    s1 += __shfl_xor(s1, 2);  s2 += __shfl_xor(s2, 2);
    s1 += __shfl_xor(s1, 4);  s2 += __shfl_xor(s2, 4);
    s1 += __shfl_xor(s1, 8);  s2 += __shfl_xor(s2, 8);
    s1 += __shfl_xor(s1, 16); s2 += __shfl_xor(s2, 16);
    s1 += __shfl_xor(s1, 32); s2 += __shfl_xor(s2, 32);
    if (lane == 0) {
      atomicAdd(&stats[bm * 2], s1);
      atomicAdd(&stats[bm * 2 + 1], s2);
    }
  } else if constexpr (EPI == 2) {
#pragma unroll
    for (int m = 0; m < 4; ++m)
#pragma unroll
      for (int n = 0; n < 4; ++n) {
        const int col = n0 + wc * 64 + n * 16 + lo;
        const float bv = bias[col];
#pragma unroll
        for (int j = 0; j < 4; ++j) {
          const int row = m0 + wr * 64 + m * 16 + hi * 4 + j;
          Obf[(size_t)row * N + col] = f2b(fmaxf(acc[m][n][j] + bv, 0.f));
        }
      }
  } else if constexpr (EPI == 3) {  // fused maxpool 16x16 -> pool[b*256 + sg*32 + dg]
#pragma unroll
    for (int m = 0; m < 4; ++m)
#pragma unroll
      for (int n = 0; n < 4; ++n) {
        const int col = n0 + wc * 64 + n * 16 + lo;
        float fv = fmaxf(fmaxf(acc[m][n][0], acc[m][n][1]),
                         fmaxf(acc[m][n][2], acc[m][n][3])) + bias[col];
        fv = fmaxf(fv, __shfl_xor(fv, 1));
        fv = fmaxf(fv, __shfl_xor(fv, 2));
        fv = fmaxf(fv, __shfl_xor(fv, 4));
        fv = fmaxf(fv, __shfl_xor(fv, 8));
        fv = fmaxf(fv, __shfl_xor(fv, 16));
        fv = fmaxf(fv, __shfl_xor(fv, 32));
        if (lane == 0)
          pool[bm * 256 + (wr * 4 + m) * 32 + (bn * 8 + wc * 4 + n)] = fv;
      }
  } else {  // EPI 4: QKV scatter. col -> (h, kind, idx); q,k row-major, v transposed
    ushort* kbp = (ushort*)Of;
    ushort* vtp = (ushort*)pool;
#pragma unroll
    for (int m = 0; m < 4; ++m)
#pragma unroll
      for (int n = 0; n < 4; ++n) {
        const int cn0 = n0 + wc * 64 + n * 16;
        const int h = cn0 / 192;
        const int rem = cn0 - h * 192;
        const int kind = rem >> 6;
        const int idx = (rem & 63) + lo;
#pragma unroll
        for (int j = 0; j < 4; ++j) {
          const int row = m0 + wr * 64 + m * 16 + hi * 4 + j;
          const size_t hb = (size_t)((row >> 7) * 8 + h) * 8192;
          const ushort v = f2b(acc[m][n][j]);
          if (kind == 0)      Obf[hb + (row & 127) * 64 + idx] = v;
          else if (kind == 1) kbp[hb + (row & 127) * 64 + idx] = v;
          else                vtp[hb + (size_t)idx * 128 + (row & 127)] = v;
        }
      }
  }
}

// ---------------------------------------------------------------- attention core
// one block per (b,head). Inputs qb,kb [bh][128][64] (q pre-scaled), vtb [bh][64][128].
// All LDS MFMA operands chunk-XOR swizzled -> <=2-way bank conflicts.
__global__ __launch_bounds__(256, 3) void attn_core(
    const ushort* __restrict__ qb, const ushort* __restrict__ kb,
    const ushort* __restrict__ vtb, ushort* __restrict__ o) {
  // smem ushorts: q [0,8192) rows of 64, k [8192,16384), vT [16384,24576) rows of 128
  // P [128][128] overlays [0,16384) after scores.
  __shared__ __align__(16) ushort smem[24576];
  const int tid = threadIdx.x, lane = tid & 63, wid = tid >> 6;
  const int lo = lane & 15, hi = lane >> 4;
  const int bh = blockIdx.x;
  const size_t base = (size_t)bh * 8192;

  // stage q,k,vT: linear LDS dest, chunk-XOR pre-swizzled global src
#pragma unroll
  for (int i = 0; i < 4; ++i) {
    const int Lb = (wid * 4 + i) * 64;
    const int L = Lb + lane;
    {
      const int r = L >> 3, c = L & 7;  // q: 8 chunks/row
      gll16(&qb[base + r * 64 + ((c ^ (r & 7)) << 3)], &smem[Lb * 8]);
      gll16(&kb[base + r * 64 + ((c ^ (r & 7)) << 3)], &smem[8192 + Lb * 8]);
    }
    {
      const int r = L >> 4, c = L & 15;  // vT: 16 chunks/row
      gll16(&vtb[base + r * 128 + ((c ^ (r & 15)) << 3)], &smem[16384 + Lb * 8]);
    }
  }
  __syncthreads();

  // ---- scores: rows [wid*32,+32) x cols 128 (q pre-scaled by 1/8)
  f32x4 sc[2][8];
#pragma unroll
  for (int m = 0; m < 2; ++m)
#pragma unroll
    for (int n = 0; n < 8; ++n) sc[m][n] = (f32x4){0.f, 0.f, 0.f, 0.f};
#pragma unroll
  for (int kt = 0; kt < 2; ++kt) {
    s16x8 aq[2], bk[8];
#pragma unroll
    for (int m = 0; m < 2; ++m) {
      const int row = wid * 32 + m * 16 + lo;
      aq[m] = *(const s16x8*)&smem[row * 64 + (((kt * 4 + hi) ^ (row & 7)) << 3)];
    }
#pragma unroll
    for (int n = 0; n < 8; ++n) {
      const int kr = n * 16 + lo;
      bk[n] = *(const s16x8*)&smem[8192 + kr * 64 + (((kt * 4 + hi) ^ (kr & 7)) << 3)];
    }
#pragma unroll
    for (int m = 0; m < 2; ++m)
#pragma unroll
      for (int n = 0; n < 8; ++n)
        sc[m][n] = __builtin_amdgcn_mfma_f32_16x16x32_bf16(aq[m], bk[n], sc[m][n], 0, 0, 0);
  }
  __syncthreads();  // q,k reads done; safe to overlay P

  // ---- softmax per row (row = wid*32 + m*16 + hi*4 + j; full row within wave)
  float inv[2][4];
#pragma unroll
  for (int m = 0; m < 2; ++m)
#pragma unroll
    for (int j = 0; j < 4; ++j) {
      float mx = sc[m][0][j];
#pragma unroll
      for (int n = 1; n < 8; ++n) mx = fmaxf(mx, sc[m][n][j]);
      mx = fmaxf(mx, __shfl_xor(mx, 1));
      mx = fmaxf(mx, __shfl_xor(mx, 2));
      mx = fmaxf(mx, __shfl_xor(mx, 4));
      mx = fmaxf(mx, __shfl_xor(mx, 8));
      float s = 0.f;
#pragma unroll
      for (int n = 0; n < 8; ++n) {
        const float p = __expf(sc[m][n][j] - mx);
        sc[m][n][j] = p;
        s += p;
      }
      s += __shfl_xor(s, 1);
      s += __shfl_xor(s, 2);
      s += __shfl_xor(s, 4);
      s += __shfl_xor(s, 8);
      inv[m][j] = 1.f / s;
    }
  // write P (chunk-XOR swizzled), overlays q+k
#pragma unroll
  for (int m = 0; m < 2; ++m)
#pragma unroll
    for (int n = 0; n < 8; ++n)
#pragma unroll
      for (int j = 0; j < 4; ++j) {
        const int row = wid * 32 + m * 16 + hi * 4 + j;
        const int col = n * 16 + lo;
        smem[row * 128 + ((((col >> 3) ^ (row & 15)) << 3) | (col & 7))] =
            f2b(sc[m][n][j]);
      }
  __syncthreads();

  // ---- PV: O[rows 32/wave][64], K=128
  f32x4 oa[2][4];
#pragma unroll
  for (int m = 0; m < 2; ++m)
#pragma unroll
    for (int n = 0; n < 4; ++n) oa[m][n] = (f32x4){0.f, 0.f, 0.f, 0.f};
#pragma unroll
  for (int kt = 0; kt < 4; ++kt) {
    s16x8 ap[2], bv[4];
#pragma unroll
    for (int m = 0; m < 2; ++m) {
      const int row = wid * 32 + m * 16 + lo;
      ap[m] = *(const s16x8*)&smem[row * 128 + (((kt * 4 + hi) ^ (row & 15)) << 3)];
    }
#pragma unroll
    for (int n = 0; n < 4; ++n) {
      const int vr = n * 16 + lo;
      bv[n] = *(const s16x8*)&smem[16384 + vr * 128 + (((kt * 4 + hi) ^ (vr & 15)) << 3)];
    }
#pragma unroll
    for (int m = 0; m < 2; ++m)
#pragma unroll
      for (int n = 0; n < 4; ++n)
        oa[m][n] = __builtin_amdgcn_mfma_f32_16x16x32_bf16(ap[m], bv[n], oa[m][n], 0, 0, 0);
  }
  const int b = bh >> 3, hd = bh & 7;
#pragma unroll
  for (int m = 0; m < 2; ++m)
#pragma unroll
    for (int n = 0; n < 4; ++n)
#pragma unroll
      for (int j = 0; j < 4; ++j) {
        const int row = wid * 32 + m * 16 + hi * 4 + j;
        const int col = n * 16 + lo;
        o[(size_t)b * 65536 + row * 512 + hd * 64 + col] = f2b(oa[m][n][j] * inv[m][j]);
      }
}

// ---------------------------------------------------------------- LN apply (fp32 in)
__global__ void ln_apply(const float* __restrict__ r, const float* __restrict__ stats,
                         const float* __restrict__ nw, const float* __restrict__ nb,
                         ushort* __restrict__ rn) {
  int i = blockIdx.x * blockDim.x + threadIdx.x;  // x4 elements
  int base = i << 2;
  if (base >= NB * NS * ND) return;
  int b = base >> 16;     // / (S*D=65536)
  int sd = base & 65535;
  float mu = stats[2 * b] * (1.f / 65536.f);
  float var = stats[2 * b + 1] * (1.f / 65536.f) - mu * mu;
  float rs = rsqrtf(var + 1e-5f);
  float4 rv = *(const float4*)(r + base);
  float4 w = *(const float4*)(nw + sd);
  float4 bb = *(const float4*)(nb + sd);
  ushort4 ov;
  ov.x = f2b((rv.x - mu) * rs * w.x + bb.x);
  ov.y = f2b((rv.y - mu) * rs * w.y + bb.y);
  ov.z = f2b((rv.z - mu) * rs * w.z + bb.z);
  ov.w = f2b((rv.w - mu) * rs * w.w + bb.w);
  *(ushort4*)(rn + base) = ov;
}

// ---------------------------------------------------------------- final fc
__global__ void fc_logsoftmax(const float* __restrict__ p, const float* __restrict__ w,
                              const float* __restrict__ bias, float* __restrict__ out) {
  int b = blockIdx.x * blockDim.x + threadIdx.x;
  if (b >= NB) return;
  float l0 = bias[0], l1 = bias[1];
  const float* pr = p + b * 256;
  for (int k = 0; k < 256; ++k) {
    float pv = pr[k];
    l0 += pv * w[2 * k];
    l1 += pv * w[2 * k + 1];
  }
  float mx = fmaxf(l0, l1);
  float lse = mx + logf(expf(l0 - mx) + expf(l1 - mx));
  out[2 * b] = l0 - lse;
  out[2 * b + 1] = l1 - lse;
}

// ---------------------------------------------------------------- launch
extern "C" void kernel_launch(void* const* d_in, const int* in_sizes, int n_in,
                              void* d_out, int out_size, void* d_ws, size_t ws_size,
                              hipStream_t stream) {
  const float* x      = (const float*)d_in[0];
  const float* emb_w  = (const float*)d_in[1];
  const float* emb_b  = (const float*)d_in[2];
  const float* WQ     = (const float*)d_in[3];
  const float* WK     = (const float*)d_in[4];
  const float* WV     = (const float*)d_in[5];
  const float* WO     = (const float*)d_in[6];
  const float* norm_w = (const float*)d_in[7];
  const float* norm_b = (const float*)d_in[8];
  const float* l1_w   = (const float*)d_in[9];
  const float* l1_b   = (const float*)d_in[10];
  const float* l2_w   = (const float*)d_in[11];
  const float* l2_b   = (const float*)d_in[12];
  const float* fc_w   = (const float*)d_in[13];
  const float* fc_b   = (const float*)d_in[14];
  float* out = (float*)d_out;
  char* ws = (char*)d_ws;

  constexpr size_t MB = 1ull << 20;
  // Lifetime-overlaid layout (peak 392 MB, same as the proven R4 footprint):
  ushort* xb    = (ushort*)(ws + 0);          // 64 MB (dead after embed)
  ushort* qb    = (ushort*)(ws + 0);          // 64 MB [bh][128][64] (over xb)
  ushort* hbuf  = (ushort*)(ws + 64 * MB);    // 64 MB (live until WO residual)
  ushort* kbuf  = (ushort*)(ws + 128 * MB);   // 64 MB [bh][128][64]
  ushort* obuf  = (ushort*)(ws + 192 * MB);   // 64 MB (attn out; read by WO gemm)
  ushort* vtb   = (ushort*)(ws + 256 * MB);   // 64 MB [bh][64][128] (dead after attn)
  float*  rbuf  = (float*)(ws + 256 * MB);    // 128 MB fp32 r (over vtb; no overlap w/ obuf)
  ushort* rnb   = (ushort*)(ws + 64 * MB);    // 64 MB (over hbuf, dead after WO gemm)
  ushort* f1    = (ushort*)(ws + 128 * MB);   // 256 MB [128,384): kbuf/obuf/rbuf dead by FFN1
  char* wb = ws + 384 * MB;
  ushort* embT  = (ushort*)(wb);                  // 512 KB
  ushort* woT   = (ushort*)(wb + 524288);         // 512 KB
  ushort* l1T   = (ushort*)(wb + 1048576);        // 2 MB
  ushort* l2T   = (ushort*)(wb + 3145728);        // 2 MB
  ushort* wqkvT = (ushort*)(wb + 5242880);        // 1.5 MB
  float*  peb   = (float*)(wb + 6815744);         // 256 KB
  float*  stats = (float*)(wb + 7077888);         // 4 KB
  float*  poolb = (float*)(wb + 7081984);         // 512 KB

  hipMemsetAsync(stats, 0, NB * 2 * sizeof(float), stream);

  conv_bf16<<<32768, 256, 0, stream>>>(x, xb, NB * NS * ND / 4);
  pe_build<<<256, 256, 0, stream>>>(peb);
  pack_t<<<1024, 256, 0, stream>>>(emb_w, embT, 512, 512);
  pack_t<<<1024, 256, 0, stream>>>(WO, woT, 512, 512);
  pack_t<<<4096, 256, 0, stream>>>(l1_w, l1T, 512, 2048);
  pack_t<<<4096, 256, 0, stream>>>(l2_w, l2T, 2048, 512);
  pack_qkv<<<3072, 256, 0, stream>>>(WQ, WK, WV, wqkvT);

  // h = x@emb_w + emb_b + PE
  gemm_bf16<0><<<2048, 256, 0, stream>>>(xb, embT, NB * NS, ND, ND,
                                         hbuf, nullptr, emb_b, peb, nullptr, nullptr, nullptr);
  // q,k,vT for all heads in one GEMM: [65536,512] @ [512,1536]
  gemm_bf16<4><<<6144, 256, 0, stream>>>(hbuf, wqkvT, NB * NS, NH * 192, ND,
                                         qb, (float*)kbuf, nullptr, nullptr, nullptr, nullptr,
                                         (float*)vtb);
  // attention core -> o
  attn_core<<<NB * NH, 256, 0, stream>>>(qb, kbuf, vtb, obuf);
  // r = o@WO + h (fp32) + LN stats
  gemm_bf16<1><<<2048, 256, 0, stream>>>(obuf, woT, NB * NS, ND, ND,
                                         nullptr, rbuf, nullptr, nullptr, hbuf, stats, nullptr);
  // rn = LN(r)
  ln_apply<<<32768, 256, 0, stream>>>(rbuf, stats, norm_w, norm_b, rnb);
  // f1 = relu(rn@l1 + b1)
  gemm_bf16<2><<<8192, 256, 0, stream>>>(rnb, l1T, NB * NS, NFF, ND,
                                         f1, nullptr, l1_b, nullptr, nullptr, nullptr, nullptr);
  // pool = maxpool16x16(f1@l2 + b2)
  gemm_bf16<3><<<2048, 256, 0, stream>>>(f1, l2T, NB * NS, ND, NFF,
                                         nullptr, nullptr, l2_b, nullptr, nullptr, nullptr, poolb);
  // logits + log_softmax
  fc_logsoftmax<<<2, 256, 0, stream>>>(poolb, fc_w, fc_b, out);
}